// Round 3
// baseline (90.363 us; speedup 1.0000x reference)
//
#include <hip/hip_runtime.h>

#define BATCH 65536
#define NSPL  64
#define CDIM  64
#define TDIM  68          // CDIM + DEGREE + 1
#define QI    67          // degree-0 intervals
#define RTN   67          // region-table entries per spline

#define TCOLS 16          // splines per block
#define TROWS 128         // rows per block
#define NTHR  256
#define KPAD  128         // global sorted-knot pitch (padded with +INF)
#define KLDS  132         // LDS pitch: 132%32==4 -> col bank offsets spread

// ============================================================================
// Sorted-region formulation (R8, proven): S(x) is piecewise-cubic with
// breakpoints at the sorted knot values; region index m = #{j: x >= t_j} over
// the ORIGINAL knots (order-independent count); prep sums active Q_i per
// region (fp64) -> RT[spline][m-1] float4; m=0/68 -> 0.
// R11 (proven, -12us): 7-step branchless binary search over sorted knots.
// R12 (null): direct scalar global I/O, fewer LDS ops -> no delta. Post-
// mortem: LDS was not binding; R12 doubled VMEM instr count (24/thread,
// scalar dword stores) -- traded pipes. Main is VMEM/streaming-path bound.
// R13: row x col-quad thread mapping -> float4 X load / float4 O store
// (1KB per wave-instr, ideal), per-lane float4 RT gather. 12 VMEM
// instrs/thread (was 24), zero scalar stores. Search: levels 1-2 from 12
// one-time register pivots, levels 3-7 from LDS (5 reads/el, ~2/bank).
// If this is null too, main is at its streaming floor (remainder =
// harness fill + reset overhead) -> roofline.
// ============================================================================

__global__ __launch_bounds__(128) void prep(const float* __restrict__ T,
                                            const float* __restrict__ C,
                                            float4* __restrict__ RT,
                                            float* __restrict__ SRT) {
    __shared__ double  td[TDIM];
    __shared__ double  cd[CDIM];
    __shared__ double  R1[QI], R2[TDIM - 2], R3[TDIM - 3];
    __shared__ double4 Qd[QI];
    __shared__ float   tf[TDIM];
    __shared__ float   srt[TDIM];

    const int s = blockIdx.x;
    const int t = threadIdx.x;

    if (t < TDIM) { float v = T[s * TDIM + t]; tf[t] = v; td[t] = (double)v; }
    if (t >= 64 && t < 64 + CDIM) cd[t - 64] = (double)C[s * CDIM + t - 64];
    __syncthreads();

    // Safe reciprocals (0/0 := 0; fp64 diff is 0 iff fp32 values equal).
    if (t < TDIM - 1) { double d = td[t + 1] - td[t]; R1[t] = (d == 0.0) ? 0.0 : 1.0 / d; }
    if (t < TDIM - 2) { double d = td[t + 2] - td[t]; R2[t] = (d == 0.0) ? 0.0 : 1.0 / d; }
    if (t < TDIM - 3) { double d = td[t + 3] - td[t]; R3[t] = (d == 0.0) ? 0.0 : 1.0 / d; }
    // Rank-sort the 68 knots (ties broken by index -> deterministic).
    if (t < TDIM) {
        float v = tf[t];
        int r = 0;
        for (int k = 0; k < TDIM; ++k)
            r += (tf[k] < v) || (tf[k] == v && k < t);
        srt[r] = v;
    }
    __syncthreads();

    // Export sorted knots, padded to 128 with +INF (INF <= x always false for
    // finite x -> count unaffected).
    {
        float v = (t < TDIM) ? srt[t] : __builtin_huge_valf();
        SRT[s * KPAD + t] = v;
    }

    // Expand Q_i: cubic for interval i, sum over <=8 Cox-de Boor lattice paths.
    if (t < QI) {
        const int i = t;
        double q0 = 0, q1 = 0, q2 = 0, q3 = 0;
        for (int j = i - 3; j <= i; ++j) {
            if (j < 0 || j > CDIM - 1) continue;
            double cj = cd[j];
            for (int b2 = 0; b2 < 2; ++b2) {
                int m2 = j + b2;
                double D3 = R3[j + b2];
                double p3 = b2 ? -D3 : D3;
                double r3 = b2 ? D3 * td[j + 4] : -D3 * td[j];
                for (int b1 = 0; b1 < 2; ++b1) {
                    int m1 = m2 + b1;
                    double D2 = R2[m2 + b1];
                    double p2 = b1 ? -D2 : D2;
                    double r2 = b1 ? D2 * td[m2 + 3] : -D2 * td[m2];
                    for (int b0 = 0; b0 < 2; ++b0) {
                        if (m1 + b0 != i) continue;   // path must end at interval i
                        double D1 = R1[m1 + b0];
                        double p1 = b0 ? -D1 : D1;
                        double r1 = b0 ? D1 * td[m1 + 2] : -D1 * td[m1];
                        double a2 = p3 * p2, a1 = p3 * r2 + r3 * p2, a0 = r3 * r2;
                        q3 += cj * (a2 * p1);
                        q2 += cj * (a2 * r1 + a1 * p1);
                        q1 += cj * (a1 * r1 + a0 * p1);
                        q0 += cj * (a0 * r1);
                    }
                }
            }
        }
        double4 q; q.x = q0; q.y = q1; q.z = q2; q.w = q3;
        Qd[i] = q;
    }
    __syncthreads();

    // Region sums: for m = t in 1..67, x* = srt[m-1]; active i <=> same fp32
    // predicates as the reference. Coefficient-wise fp64 sum -> fp32 cubic.
    if (t >= 1 && t <= RTN) {
        const float xs = srt[t - 1];
        double a0 = 0, a1 = 0, a2 = 0, a3 = 0;
        for (int i = 0; i < QI; ++i) {
            if (tf[i] <= xs && xs < tf[i + 1]) {
                double4 q = Qd[i];
                a0 += q.x; a1 += q.y; a2 += q.z; a3 += q.w;
            }
        }
        float4 v; v.x = (float)a0; v.y = (float)a1; v.z = (float)a2; v.w = (float)a3;
        RT[s * RTN + (t - 1)] = v;
    }
}

__global__ __launch_bounds__(NTHR, 8) void bspline_main(const float* __restrict__ X,
                                                        const float4* __restrict__ RT,
                                                        const float* __restrict__ SRT,
                                                        float* __restrict__ O) {
    __shared__ float ks[TCOLS * KLDS];   // 8,448 B: sorted+padded knots per column

    const int tid = threadIdx.x;
    const int r0  = blockIdx.x * TROWS;
    const int s0  = blockIdx.y * TCOLS;

    // Stage sorted knots: 16 cols x 128 floats = 512 float4 pieces, 2/thread.
    {
        const float4* src = (const float4*)(SRT + s0 * KPAD);
        #pragma unroll
        for (int it = 0; it < 2; ++it) {
            int e = tid + it * NTHR;
            int c = e >> 5, p = e & 31;          // col, float4-piece within col
            float4 v = src[c * 32 + p];
            *(float4*)(ks + c * KLDS + p * 4) = v;
        }
    }
    __syncthreads();

    // Thread = (row-slot rs, col-quad q): one float4 covers 4 consecutive
    // splines of one row. Wave = 16 rows x 16 cols = 16 full 64B sectors =
    // 1KB per load/store instr (ideal). 2 rows/thread (rs, rs+64).
    const int q  = tid & 3;
    const int rs = tid >> 2;                     // 0..63
    const int c0 = q * 4;                        // first of this thread's 4 cols

    // Search levels 1-2 from registers (12 one-time LDS loads, amortized
    // over 8 elements). Levels 3-7 from LDS: 5 reads/element, banks
    // (4c+idx)%32 spread ~2/bank across the wave (free).
    float pv1[4], pv2a[4], pv2b[4];
    #pragma unroll
    for (int cc = 0; cc < 4; ++cc) {
        const float* kc = ks + (c0 + cc) * KLDS;
        pv1[cc]  = kc[63];
        pv2a[cc] = kc[31];
        pv2b[cc] = kc[95];
    }

    const float4* xp = (const float4*)(X + (r0 + rs) * NSPL + s0) + q;
    float4*       op = (float4*)(O + (r0 + rs) * NSPL + s0) + q;
    const int rstride = NSPL / 4;                // row stride in float4 units

    #pragma unroll
    for (int h = 0; h < 2; ++h) {                // rows rs and rs+64
        const int roff = h * 64 * rstride;
        const float4 xv = xp[roff];
        float y[4];
        const float xs[4] = { xv.x, xv.y, xv.z, xv.w };

        #pragma unroll
        for (int cc = 0; cc < 4; ++cc) {
            const float x = xs[cc];
            const float* kc = ks + (c0 + cc) * KLDS;

            // n = #{k: srt[k] <= x} (== #{j: x >= t_j}, multiset equality).
            unsigned n = (pv1[cc] <= x) ? 64u : 0u;
            float t2 = n ? pv2b[cc] : pv2a[cc];
            n += (t2 <= x) ? 32u : 0u;           // n ∈ {0,32,64,96}
            #pragma unroll
            for (int st = 16; st >= 1; st >>= 1) {   // 5 LDS reads (idx <= 119)
                float v = kc[n + st - 1];
                n = (v <= x) ? n + st : n;
            }

            // Region m = n; table entry m-1 for m in [1,67]; m=0/68 -> 0.
            unsigned i = n - 1u; i = (i > 66u) ? 66u : i;   // wrap(n=0)->66 too
            float4 p = RT[(s0 + c0 + cc) * RTN + i];        // L1/L2 VMEM gather
            float yy = fmaf(fmaf(fmaf(p.w, x, p.z), x, p.y), x, p.x);
            y[cc] = (n - 1u < 67u) ? yy : 0.f;   // m=0 or m=68 -> outside knots
        }

        float4 yv; yv.x = y[0]; yv.y = y[1]; yv.z = y[2]; yv.w = y[3];
        op[roff] = yv;
    }
}

extern "C" void kernel_launch(void* const* d_in, const int* in_sizes, int n_in,
                              void* d_out, int out_size, void* d_ws, size_t ws_size,
                              hipStream_t stream) {
    const float* X = (const float*)d_in[0];  // [65536, 64]
    const float* T = (const float*)d_in[1];  // [64, 68]
    const float* C = (const float*)d_in[2];  // [64, 64]
    float* O = (float*)d_out;                // [65536, 64]
    float4* RT = (float4*)d_ws;              // 64*67 float4 = 68,608 B
    float* SRT = (float*)((char*)d_ws + NSPL * RTN * sizeof(float4));  // 64*128 f32 = 32 KB

    prep<<<NSPL, 128, 0, stream>>>(T, C, RT, SRT);
    dim3 grid(BATCH / TROWS, NSPL / TCOLS);  // (512, 4) = 2048 blocks, 8/CU resident
    bspline_main<<<grid, NTHR, 0, stream>>>(X, RT, SRT, O);
}

// Round 4
// 87.975 us; speedup vs baseline: 1.0271x; 1.0271x over previous
//
#include <hip/hip_runtime.h>

#define BATCH 65536
#define NSPL  64
#define CDIM  64
#define TDIM  68          // CDIM + DEGREE + 1
#define QI    67          // degree-0 intervals
#define RTN   67          // region-table entries per spline

#define TCOLS 16          // splines per block
#define TROWS 128         // rows per block (8 rows/thread)
#define NTHR  256
#define KPAD  128         // global sorted-knot pitch (padded with +INF)
#define KLDS  132         // LDS pitch: 132%32==4 -> 16 cols spread 2-per-bank

// ============================================================================
// Sorted-region formulation (R8, proven): S(x) is piecewise-cubic with
// breakpoints at the sorted knot values; region index m = #{j: x >= t_j} over
// the ORIGINAL knots (order-independent count); prep sums active Q_i per
// region (fp64) -> RT[spline][m-1] float4; m=0/68 -> 0.
// R11 (proven, -12us): 7-step branchless binary search over sorted knots
// (multiset count == linear count) replaced the 68-iter scan.
// R12 (null vs R11, best overall 88.67us): direct per-lane scalar I/O,
// search levels 1-3 in 7 register pivots, 4 LDS reads/element.
// R13 (REGRESSED +1.7us): float4 I/O with 4 serial per-thread searches --
// halved VMEM instr count, no gain (streaming BYTES bind, not instrs);
// lengthened dependent-LDS chains at equal occupancy -> net loss. REVERTED.
// R14 = exact R12 revert. Decomposition: timed region = 44us harness fill
// + ~30us harness resets/gaps + main ~8us (HBM floor 5.6us for 33.5MB) +
// prep ~3us. Three consecutive pipe changes on main = {null, null, -1.7}:
// main is at its streaming floor. If this lands ~88.5+-1 -> ROOFLINE.
// ============================================================================

__global__ __launch_bounds__(128) void prep(const float* __restrict__ T,
                                            const float* __restrict__ C,
                                            float4* __restrict__ RT,
                                            float* __restrict__ SRT) {
    __shared__ double  td[TDIM];
    __shared__ double  cd[CDIM];
    __shared__ double  R1[QI], R2[TDIM - 2], R3[TDIM - 3];
    __shared__ double4 Qd[QI];
    __shared__ float   tf[TDIM];
    __shared__ float   srt[TDIM];

    const int s = blockIdx.x;
    const int t = threadIdx.x;

    if (t < TDIM) { float v = T[s * TDIM + t]; tf[t] = v; td[t] = (double)v; }
    if (t >= 64 && t < 64 + CDIM) cd[t - 64] = (double)C[s * CDIM + t - 64];
    __syncthreads();

    // Safe reciprocals (0/0 := 0; fp64 diff is 0 iff fp32 values equal).
    if (t < TDIM - 1) { double d = td[t + 1] - td[t]; R1[t] = (d == 0.0) ? 0.0 : 1.0 / d; }
    if (t < TDIM - 2) { double d = td[t + 2] - td[t]; R2[t] = (d == 0.0) ? 0.0 : 1.0 / d; }
    if (t < TDIM - 3) { double d = td[t + 3] - td[t]; R3[t] = (d == 0.0) ? 0.0 : 1.0 / d; }
    // Rank-sort the 68 knots (ties broken by index -> deterministic).
    if (t < TDIM) {
        float v = tf[t];
        int r = 0;
        for (int k = 0; k < TDIM; ++k)
            r += (tf[k] < v) || (tf[k] == v && k < t);
        srt[r] = v;
    }
    __syncthreads();

    // Export sorted knots, padded to 128 with +INF (INF <= x always false for
    // finite x -> count unaffected).
    {
        float v = (t < TDIM) ? srt[t] : __builtin_huge_valf();
        SRT[s * KPAD + t] = v;
    }

    // Expand Q_i: cubic for interval i, sum over <=8 Cox-de Boor lattice paths.
    if (t < QI) {
        const int i = t;
        double q0 = 0, q1 = 0, q2 = 0, q3 = 0;
        for (int j = i - 3; j <= i; ++j) {
            if (j < 0 || j > CDIM - 1) continue;
            double cj = cd[j];
            for (int b2 = 0; b2 < 2; ++b2) {
                int m2 = j + b2;
                double D3 = R3[j + b2];
                double p3 = b2 ? -D3 : D3;
                double r3 = b2 ? D3 * td[j + 4] : -D3 * td[j];
                for (int b1 = 0; b1 < 2; ++b1) {
                    int m1 = m2 + b1;
                    double D2 = R2[m2 + b1];
                    double p2 = b1 ? -D2 : D2;
                    double r2 = b1 ? D2 * td[m2 + 3] : -D2 * td[m2];
                    for (int b0 = 0; b0 < 2; ++b0) {
                        if (m1 + b0 != i) continue;   // path must end at interval i
                        double D1 = R1[m1 + b0];
                        double p1 = b0 ? -D1 : D1;
                        double r1 = b0 ? D1 * td[m1 + 2] : -D1 * td[m1];
                        double a2 = p3 * p2, a1 = p3 * r2 + r3 * p2, a0 = r3 * r2;
                        q3 += cj * (a2 * p1);
                        q2 += cj * (a2 * r1 + a1 * p1);
                        q1 += cj * (a1 * r1 + a0 * p1);
                        q0 += cj * (a0 * r1);
                    }
                }
            }
        }
        double4 q; q.x = q0; q.y = q1; q.z = q2; q.w = q3;
        Qd[i] = q;
    }
    __syncthreads();

    // Region sums: for m = t in 1..67, x* = srt[m-1]; active i <=> same fp32
    // predicates as the reference. Coefficient-wise fp64 sum -> fp32 cubic.
    if (t >= 1 && t <= RTN) {
        const float xs = srt[t - 1];
        double a0 = 0, a1 = 0, a2 = 0, a3 = 0;
        for (int i = 0; i < QI; ++i) {
            if (tf[i] <= xs && xs < tf[i + 1]) {
                double4 q = Qd[i];
                a0 += q.x; a1 += q.y; a2 += q.z; a3 += q.w;
            }
        }
        float4 v; v.x = (float)a0; v.y = (float)a1; v.z = (float)a2; v.w = (float)a3;
        RT[s * RTN + (t - 1)] = v;
    }
}

__global__ __launch_bounds__(NTHR, 8) void bspline_main(const float* __restrict__ X,
                                                        const float4* __restrict__ RT,
                                                        const float* __restrict__ SRT,
                                                        float* __restrict__ O) {
    __shared__ float ks[TCOLS * KLDS];   // 8,448 B: sorted+padded knots per column

    const int tid = threadIdx.x;
    const int r0  = blockIdx.x * TROWS;
    const int s0  = blockIdx.y * TCOLS;

    // Stage sorted knots: 16 cols x 128 floats = 512 float4 pieces, 2/thread.
    // Global side coalesced (1KB/wave-instr); one-time LDS writes.
    {
        const float4* src = (const float4*)(SRT + s0 * KPAD);
        #pragma unroll
        for (int it = 0; it < 2; ++it) {
            int e = tid + it * NTHR;
            int c = e >> 5, p = e & 31;          // col, float4-piece within col
            float4 v = src[c * 32 + p];
            *(float4*)(ks + c * KLDS + p * 4) = v;
        }
    }
    __syncthreads();

    // Lane = (row-slot rs, spline col c). Wave = 4 rows x 16 cols: x loads and
    // y stores are 4 full 64B sectors per wave-instr (== ideal dense sector
    // count -> zero coalescing loss).
    const int c  = tid & 15;
    const int rs = tid >> 4;                     // 0..15
    const float* kc = ks + c * KLDS;             // bank (4c+idx)%32: 16 cols, 2/bank

    // Search levels 1-3 from registers (one-time LDS load, amortized 8 rows).
    const float pv1  = kc[63];
    const float pv2a = kc[31], pv2b = kc[95];
    const float pv3a = kc[15], pv3b = kc[47], pv3c = kc[79], pv3d = kc[111];

    const float4* rts = RT + (s0 + c) * RTN;     // per-lane base: VMEM gather path
    const float*  xp  = X + (r0 + rs) * NSPL + s0 + c;
    float*        op  = O + (r0 + rs) * NSPL + s0 + c;

    #pragma unroll
    for (int j = 0; j < 4; ++j) {                // 2 interleaved rows per iter
        const int ra = (32 * j) * NSPL, rb = (32 * j + 16) * NSPL;
        const float x0 = xp[ra];
        const float x1 = xp[rb];

        // n = #{k: srt[k] <= x} (== #{j: x >= t_j}, multiset equality, proven).
        unsigned n0 = (pv1 <= x0) ? 64u : 0u;
        unsigned n1 = (pv1 <= x1) ? 64u : 0u;
        float q0 = n0 ? pv2b : pv2a;
        float q1 = n1 ? pv2b : pv2a;
        n0 += (q0 <= x0) ? 32u : 0u;             // n ∈ {0,32,64,96}
        n1 += (q1 <= x1) ? 32u : 0u;
        float a0 = (n0 & 32u) ? pv3b : pv3a;     // kc[n+15] select tree
        float b0 = (n0 & 32u) ? pv3d : pv3c;
        float a1 = (n1 & 32u) ? pv3b : pv3a;
        float b1 = (n1 & 32u) ? pv3d : pv3c;
        float r0v = (n0 & 64u) ? b0 : a0;
        float r1v = (n1 & 64u) ? b1 : a1;
        n0 += (r0v <= x0) ? 16u : 0u;            // n ∈ {0,16,...,112}
        n1 += (r1v <= x1) ? 16u : 0u;
        #pragma unroll
        for (int st = 8; st >= 1; st >>= 1) {    // 4 LDS reads per x (max idx 119)
            float v0 = kc[n0 + st - 1];
            float v1 = kc[n1 + st - 1];
            n0 = (v0 <= x0) ? n0 + st : n0;
            n1 = (v1 <= x1) ? n1 + st : n1;
        }

        // Region m = n; table entry m-1 for m in [1,67]; m=0/68 -> 0.
        unsigned i0 = n0 - 1u; i0 = (i0 > 66u) ? 66u : i0;   // wrap(n=0)->66 too
        unsigned i1 = n1 - 1u; i1 = (i1 > 66u) ? 66u : i1;
        float4 p0 = rts[i0];                     // L1/L2-resident VMEM gather
        float4 p1 = rts[i1];
        float y0 = fmaf(fmaf(fmaf(p0.w, x0, p0.z), x0, p0.y), x0, p0.x);
        float y1 = fmaf(fmaf(fmaf(p1.w, x1, p1.z), x1, p1.y), x1, p1.x);
        y0 = (n0 - 1u < 67u) ? y0 : 0.f;         // m=0 or m=68 -> outside knots
        y1 = (n1 - 1u < 67u) ? y1 : 0.f;
        op[ra] = y0;
        op[rb] = y1;
    }
}

extern "C" void kernel_launch(void* const* d_in, const int* in_sizes, int n_in,
                              void* d_out, int out_size, void* d_ws, size_t ws_size,
                              hipStream_t stream) {
    const float* X = (const float*)d_in[0];  // [65536, 64]
    const float* T = (const float*)d_in[1];  // [64, 68]
    const float* C = (const float*)d_in[2];  // [64, 64]
    float* O = (float*)d_out;                // [65536, 64]
    float4* RT = (float4*)d_ws;              // 64*67 float4 = 68,608 B
    float* SRT = (float*)((char*)d_ws + NSPL * RTN * sizeof(float4));  // 64*128 f32 = 32 KB

    prep<<<NSPL, 128, 0, stream>>>(T, C, RT, SRT);
    dim3 grid(BATCH / TROWS, NSPL / TCOLS);  // (512, 4) = 2048 blocks, 8/CU resident
    bspline_main<<<grid, NTHR, 0, stream>>>(X, RT, SRT, O);
}